// Round 5
// baseline (170.440 us; speedup 1.0000x reference)
//
#include <hip/hip_runtime.h>
#include <hip/hip_bf16.h>

// B=64,C=4 -> BF=256, N=1024, G=32, D=3, K=512
#define BFN   256
#define NPTS  1024
#define KSEL  512
#define GD    96          // G*D floats per patch row
#define ROW4  24          // GD/4 float4s per patch row (384 B)

typedef unsigned long long u64;

// ---- selection: rank table (inverse permutation) + centers output ----
__global__ __launch_bounds__(1024)
void sel_kernel(const float* __restrict__ centers,
                const int*   __restrict__ center_idx,
                int* __restrict__ rank_ws,
                float* __restrict__ out_centers)
{
    __shared__ u64 lds[NPTS];
    const int bf = blockIdx.x;
    const int t  = threadIdx.x;

    // explicit init: unselected rows must read as negative (don't rely on poison)
    rank_ws[bf * NPTS + t] = -1;

    const float* cbase = centers + (size_t)bf * NPTS * 3;
    const int qi = center_idx[bf];
    const float q0 = cbase[qi * 3 + 0], q1 = cbase[qi * 3 + 1], q2 = cbase[qi * 3 + 2];
    const float c0 = cbase[t * 3 + 0],  c1 = cbase[t * 3 + 1],  c2 = cbase[t * 3 + 2];

    // f64 d2 from f32 inputs is exact -> true ordering, matches numpy ref
    // (round-3 verified: absmax 0.0).
    const double e0 = (double)q0 - (double)c0;
    const double e1 = (double)q1 - (double)c1;
    const double e2 = (double)q2 - (double)c2;
    const double d2 = e0 * e0 + e1 * e1 + e2 * e2;

    // d2>=0 -> f64 bits monotone; low 10 bits = index (stable tie-break).
    u64 key = (((u64)__double_as_longlong(d2)) & ~0x3FFull) | (u64)t;

    // bitonic sort: strides<=32 in-wave shfl (no barrier), strides>=64 via LDS.
    for (int size = 2; size <= NPTS; size <<= 1) {
        const bool dir = (t & size) != 0;
        for (int stride = size >> 1; stride > 0; stride >>= 1) {
            u64 other;
            if (stride >= 64) {
                __syncthreads();
                lds[t] = key;
                __syncthreads();
                other = lds[t ^ stride];
            } else {
                other = __shfl_xor(key, stride, 64);
            }
            const bool upper    = (t & stride) != 0;
            const bool keep_min = (upper == dir);
            const bool mine_lt  = key < other;       // keys unique
            key = (keep_min == mine_lt) ? key : other;
        }
    }
    __syncthreads();   // also orders the rank_ws init vs the scatter below

    if (t < KSEL) {
        const int idx = (int)(key & 0x3FFull);
        rank_ws[bf * NPTS + idx] = t;              // inverse permutation
        // centers: 12KB tile is L1-hot (read at kernel start); seq write
        const float* cs = cbase + (size_t)idx * 3;
        float* oc = out_centers + ((size_t)bf * KSEL + t) * 3;
        oc[0] = cs[0]; oc[1] = cs[1]; oc[2] = cs[2];
    }
}

// ---- gather: STREAM-read patches sequentially, scatter-write by rank ----
// 4 blocks per bf, 256 source rows each: reads fully coalesced; writes land
// in a 196KB per-bf window (L2-absorbed, drains near-sequential).
__global__ __launch_bounds__(256)
void gather_kernel(const float4* __restrict__ patches4,
                   const int*    __restrict__ rank_ws,
                   float4*       __restrict__ out_p4)
{
    __shared__ int rank_s[256];
    const int b     = blockIdx.x;        // 0..1023
    const int bf    = b >> 2;
    const int chunk = b & 3;
    const int t     = threadIdx.x;

    rank_s[t] = rank_ws[bf * NPTS + chunk * 256 + t];
    __syncthreads();

    const float4* src = patches4 + ((size_t)bf * NPTS + (size_t)chunk * 256) * ROW4;
    float4*       dst = out_p4   + (size_t)bf * KSEL * ROW4;

    #pragma unroll
    for (int it = 0; it < 24; ++it) {
        const int flat = it * 256 + t;           // [0, 6144) = 256 rows * 24
        const float4 v = src[flat];              // sequential across block
        const int row  = flat / 24;              // magic-mul (const divisor)
        const int lane = flat - row * 24;
        const int r    = rank_s[row];
        if (r >= 0) dst[(size_t)r * ROW4 + lane] = v;   // scatter in 196KB window
    }
}

extern "C" void kernel_launch(void* const* d_in, const int* in_sizes, int n_in,
                              void* d_out, int out_size, void* d_ws, size_t ws_size,
                              hipStream_t stream)
{
    const float* patches    = (const float*)d_in[0];
    const float* centers    = (const float*)d_in[1];
    const int*   center_idx = (const int*)d_in[2];
    // d_in[3] is K (=512), static; hardcoded as KSEL.

    float* out_patches = (float*)d_out;                           // BF*K*G*D
    float* out_centers = (float*)d_out + (size_t)BFN * KSEL * GD; // BF*K*D
    int*   rank_ws     = (int*)d_ws;                              // BF*N ints = 1MB

    sel_kernel<<<BFN, 1024, 0, stream>>>(centers, center_idx, rank_ws, out_centers);
    gather_kernel<<<BFN * 4, 256, 0, stream>>>((const float4*)patches, rank_ws,
                                               (float4*)out_patches);
}